// Round 13
// baseline (1288.553 us; speedup 1.0000x reference)
//
#include <hip/hip_runtime.h>
#include <math.h>

#define C      128
#define C2U    64         // uints (2x bf16) per row
#define BSH    6          // 64 nodes per bucket
#define BNODES 64
#define CHUNKE 16384      // edges per coarse block

typedef __attribute__((ext_vector_type(8))) short bf16x8;   // 8 bf16 = 4 VGPR
typedef __attribute__((ext_vector_type(4))) float f32x4;

union UV { uint4 u; bf16x8 h; };

// ---- bf16 helpers (manual RNE) ----
__device__ __forceinline__ unsigned int f2bf(float f) {
    unsigned int u = __float_as_uint(f);
    return (u + 0x7fffu + ((u >> 16) & 1u)) >> 16;
}
__device__ __forceinline__ float bflo(unsigned int v) { return __uint_as_float(v << 16); }
__device__ __forceinline__ float bfhi(unsigned int v) { return __uint_as_float(v & 0xffff0000u); }

// ---------------- a1: coarse histogram (LDS atomics only) ----------------
__global__ __launch_bounds__(256) void ngl_chist_kernel(
        const int* __restrict__ dst, int E, int NBUCK, int NBLK, int* __restrict__ cnt) {
    extern __shared__ int h[];
    for (int i = threadIdx.x; i < NBUCK; i += 256) h[i] = 0;
    __syncthreads();
    int base = blockIdx.x * CHUNKE;
    int end = base + CHUNKE; if (end > E) end = E;
    for (int i = base + threadIdx.x; i < end; i += 256)
        atomicAdd(&h[dst[i] >> BSH], 1);
    __syncthreads();
    for (int i = threadIdx.x; i < NBUCK; i += 256)
        cnt[i * NBLK + blockIdx.x] = h[i];
}

// ---------------- a2a: partial sums for scan; also hosts W -> W^T bf16 ----------------
__global__ __launch_bounds__(256) void ngl_s1_kernel(const int* __restrict__ in,
                                                     int* __restrict__ bsum, int M,
                                                     const float* __restrict__ W,
                                                     unsigned int* __restrict__ Wt) {
    int g = blockIdx.x * 256 + threadIdx.x;
    if (g < C * C2U) {
        int col = g >> 6, k2 = g & 63;
        float w0 = W[(2 * k2) * C + col];
        float w1 = W[(2 * k2 + 1) * C + col];
        Wt[col * C2U + k2] = f2bf(w0) | (f2bf(w1) << 16);
    }

    __shared__ int red[256];
    int t = threadIdx.x;
    int base = blockIdx.x * 1024 + t * 4;
    int s = 0;
    #pragma unroll
    for (int j = 0; j < 4; ++j) {
        int i = base + j;
        if (i < M) s += in[i];
    }
    red[t] = s;
    __syncthreads();
    for (int o = 128; o > 0; o >>= 1) {
        if (t < o) red[t] += red[t + o];
        __syncthreads();
    }
    if (t == 0) bsum[blockIdx.x] = red[0];
}

// ---------------- a2b: exclusive scan (redundant block-sum scan in LDS) ----------------
__global__ __launch_bounds__(256) void ngl_s2_kernel(
        const int* __restrict__ in, const int* __restrict__ bsum,
        int* __restrict__ out, int M, int NB) {
    __shared__ int pre[256];
    __shared__ int red[256];
    int t = threadIdx.x;
    pre[t] = (t < NB) ? bsum[t] : 0;
    __syncthreads();
    for (int o = 1; o < 256; o <<= 1) {
        int v = 0;
        if (t >= o) v = pre[t - o];
        __syncthreads();
        if (t >= o) pre[t] += v;
        __syncthreads();
    }
    int boff = (blockIdx.x == 0) ? 0 : pre[blockIdx.x - 1];

    int base = blockIdx.x * 1024 + t * 4;
    int v[4];
    int s = 0;
    #pragma unroll
    for (int j = 0; j < 4; ++j) {
        int i = base + j;
        v[j] = (i < M) ? in[i] : 0;
        s += v[j];
    }
    red[t] = s;
    __syncthreads();
    for (int o = 1; o < 256; o <<= 1) {
        int u = 0;
        if (t >= o) u = red[t - o];
        __syncthreads();
        if (t >= o) red[t] += u;
        __syncthreads();
    }
    int run = boff + ((t == 0) ? 0 : red[t - 1]);
    #pragma unroll
    for (int j = 0; j < 4; ++j) {
        int i = base + j;
        if (i < M) {
            out[i] = run;
            run += v[j];
        }
    }
}

// ---------------- a3: coarse scatter; pk = src | dstloc<<17 (loc 6 bits) ----------------
__global__ __launch_bounds__(256) void ngl_cscat_kernel(
        const int* __restrict__ src, const int* __restrict__ dst, int E,
        int NBUCK, int NBLK, const int* __restrict__ cntoff,
        unsigned int* __restrict__ pk) {
    extern __shared__ int cur[];
    int blk = blockIdx.x;
    for (int i = threadIdx.x; i < NBUCK; i += 256) cur[i] = cntoff[i * NBLK + blk];
    __syncthreads();
    int base = blk * CHUNKE;
    int end = base + CHUNKE; if (end > E) end = E;
    for (int i = base + threadIdx.x; i < end; i += 256) {
        int d = dst[i];
        int b = d >> BSH;
        int pos = atomicAdd(&cur[b], 1);
        pk[pos] = (unsigned int)src[i] | ((unsigned int)(d & (BNODES - 1)) << 17);
    }
}

// ---------------- f1cvt: per-bucket hist -> dis ; convert bucket's x rows -> xh ----------------
__global__ __launch_bounds__(256) void ngl_f1cvt_kernel(
        const unsigned int* __restrict__ pk, const int* __restrict__ cntoff,
        int NBLK, int E, int N,
        const float4* __restrict__ x4, float* __restrict__ dis,
        uint4* __restrict__ xh4) {
    __shared__ int h[BNODES];
    __shared__ float dl[BNODES];
    int b = blockIdx.x, nb = gridDim.x;
    int s = cntoff[b * NBLK];
    int e = (b + 1 < nb) ? cntoff[(b + 1) * NBLK] : E;
    int t = threadIdx.x;
    if (t < BNODES) h[t] = 0;
    __syncthreads();
    for (int i = s + t; i < e; i += 256)
        atomicAdd(&h[pk[i] >> 17], 1);
    __syncthreads();
    if (t < BNODES) {
        int n = b * BNODES + t;
        float d = rsqrtf((float)(h[t] + 1));
        dl[t] = d;
        if (n < N) dis[n] = d;
    }
    __syncthreads();
    // convert: thread t -> row r = t>>2, quarter q = t&3 (32 floats -> 4 uint4)
    int r = t >> 2, q = t & 3;
    int n = b * BNODES + r;
    if (n < N) {
        float d = dl[r];
        const float4* xr = x4 + (long long)n * 32 + q * 8;
        uint4* xo = xh4 + (long long)n * 16 + q * 4;
        #pragma unroll
        for (int j = 0; j < 4; ++j) {
            float4 a = xr[2 * j], bb = xr[2 * j + 1];
            uint4 o;
            o.x = f2bf(a.x * d) | (f2bf(a.y * d) << 16);
            o.y = f2bf(a.z * d) | (f2bf(a.w * d) << 16);
            o.z = f2bf(bb.x * d) | (f2bf(bb.y * d) << 16);
            o.w = f2bf(bb.z * d) | (f2bf(bb.w * d) << 16);
            xo[j] = o;
        }
    }
}

// ---------------- fused gather: block = bucket, LDS fp32 accumulate ----------------
// acc layout: [loc][half][lane64] -> lo parts at [loc*128+lane], hi at [loc*128+64+lane]
// (2 lanes/bank aliasing = free). agg[n] = bf16( dis[n] * (xh[n] + sum xh[src]) )
__global__ __launch_bounds__(256) void ngl_gather_kernel(
        const unsigned int* __restrict__ xh, const float* __restrict__ dis,
        const unsigned int* __restrict__ pk, const int* __restrict__ cntoff,
        int NBLK, int E, int N, unsigned int* __restrict__ agg) {
    __shared__ float acc[BNODES * 128];   // 32 KB
    int b = blockIdx.x, nb = gridDim.x;
    int s = cntoff[b * NBLK];
    int e = (b + 1 < nb) ? cntoff[(b + 1) * NBLK] : E;
    int t = threadIdx.x;
    for (int i = t; i < BNODES * 128; i += 256) acc[i] = 0.f;
    __syncthreads();

    int w = t >> 6, lane = t & 63;
    int base = s + w * 4;
    if (base < e) {
        unsigned int cp[4];
        {
            int m = e - base; if (m > 4) m = 4;
            #pragma unroll
            for (int k = 0; k < 4; ++k) cp[k] = pk[base + (k < m ? k : m - 1)];
        }
        while (base < e) {
            int nbase = base + 16;
            unsigned int np[4];
            if (nbase < e) {
                int m2 = e - nbase; if (m2 > 4) m2 = 4;
                #pragma unroll
                for (int k = 0; k < 4; ++k) np[k] = pk[nbase + (k < m2 ? k : m2 - 1)];
            }
            int m = e - base; if (m > 4) m = 4;
            unsigned int vv[4];
            #pragma unroll
            for (int k = 0; k < 4; ++k)
                vv[k] = xh[(long long)(cp[k] & 0x1FFFFu) * C2U + lane];
            #pragma unroll
            for (int k = 0; k < 4; ++k) {
                if (k < m) {
                    int loc = (int)(cp[k] >> 17);
                    atomicAdd(&acc[loc * 128 + lane],      bflo(vv[k]));
                    atomicAdd(&acc[loc * 128 + 64 + lane], bfhi(vv[k]));
                }
            }
            #pragma unroll
            for (int k = 0; k < 4; ++k) cp[k] = np[k];
            base = nbase;
        }
    }
    __syncthreads();

    // epilogue: thread t -> node r2 = t>>2, quarter q2 = t&3 -> 16 uints
    int r2 = t >> 2, q2 = t & 3;
    int n = b * BNODES + r2;
    if (n < N) {
        float d = dis[n];
        #pragma unroll
        for (int j = 0; j < 16; ++j) {
            int u = q2 * 16 + j;
            unsigned int sv = xh[(long long)n * C2U + u];
            float ax = acc[r2 * 128 + u]      + bflo(sv);
            float ay = acc[r2 * 128 + 64 + u] + bfhi(sv);
            agg[(long long)n * C2U + u] = f2bf(ax * d) | (f2bf(ay * d) << 16);
        }
    }
}

__device__ __forceinline__ float silu1(float v) {
    return v / (1.0f + __expf(-v));
}

// ---------------- MFMA GEMM: out = silu(agg @ W + b) ----------------
__global__ __launch_bounds__(256, 2) void ngl_mfma_gemm_kernel(
        const uint4* __restrict__ agg4, const uint4* __restrict__ wt4,
        const float* __restrict__ bias, float* __restrict__ out,
        int N, int tiles_total) {
    int wid  = threadIdx.x >> 6;
    int lane = threadIdx.x & 63;
    int r  = lane & 15;       // row-in-tile (A) / col-in-tile (B,D)
    int kg = lane >> 4;       // k-group 0..3

    bf16x8 bfr[8][4];
    #pragma unroll
    for (int nt = 0; nt < 8; ++nt) {
        #pragma unroll
        for (int kk = 0; kk < 4; ++kk) {
            UV u; u.u = wt4[(nt * 16 + r) * 16 + kk * 4 + kg];
            bfr[nt][kk] = u.h;
        }
    }
    float bv[8];
    #pragma unroll
    for (int nt = 0; nt < 8; ++nt) bv[nt] = bias[nt * 16 + r];

    for (int tile = blockIdx.x * 4 + wid; tile < tiles_total; tile += gridDim.x * 4) {
        int row0 = tile * 16;
        int arow = row0 + r;

        bf16x8 afr[4];
        #pragma unroll
        for (int kk = 0; kk < 4; ++kk) {
            UV u;
            u.u = (arow < N) ? agg4[(long long)arow * 16 + kk * 4 + kg]
                             : make_uint4(0, 0, 0, 0);
            afr[kk] = u.h;
        }

        f32x4 acc[8];
        #pragma unroll
        for (int nt = 0; nt < 8; ++nt) acc[nt] = (f32x4){0.f, 0.f, 0.f, 0.f};

        #pragma unroll
        for (int kk = 0; kk < 4; ++kk) {
            #pragma unroll
            for (int nt = 0; nt < 8; ++nt) {
                acc[nt] = __builtin_amdgcn_mfma_f32_16x16x32_bf16(
                    afr[kk], bfr[nt][kk], acc[nt], 0, 0, 0);
            }
        }

        #pragma unroll
        for (int nt = 0; nt < 8; ++nt) {
            #pragma unroll
            for (int j = 0; j < 4; ++j) {
                int rr = row0 + kg * 4 + j;
                if (rr < N)
                    __builtin_nontemporal_store(
                        silu1(acc[nt][j] + bv[nt]),
                        &out[(long long)rr * C + nt * 16 + r]);
            }
        }
    }
}

extern "C" void kernel_launch(void* const* d_in, const int* in_sizes, int n_in,
                              void* d_out, int out_size, void* d_ws, size_t ws_size,
                              hipStream_t stream) {
    const float* x = (const float*)d_in[0];
    const int*   ei = (const int*)d_in[1];
    const float* W = (const float*)d_in[2];
    const float* b = (const float*)d_in[3];

    int N = in_sizes[0] / C;
    int E = in_sizes[1] / 2;
    const int* src = ei;
    const int* dst = ei + E;

    int NBUCK = (N + BNODES - 1) / BNODES;        // 1563
    int NBLK  = (E + CHUNKE - 1) / CHUNKE;        // 98
    int M     = NBUCK * NBLK;                     // 153,174
    int NB2   = (M + 1023) / 1024;                // 150 (<=256 required)

    char* ws = (char*)d_ws;
    size_t off = 0;
    unsigned int* xh = (unsigned int*)(ws + off);  off += (size_t)N * C * 2;  // 25.6 MB
    unsigned int* agg = (unsigned int*)(ws + off); off += (size_t)N * C * 2;  // 25.6 MB
    unsigned int* pk = (unsigned int*)(ws + off);  off += (size_t)E * 4;      // 6.4 MB
    int* cnt = (int*)(ws + off);                   off += (size_t)M * 4;      // 0.6 MB
    int* cntoff = (int*)(ws + off);                off += (size_t)M * 4;      // 0.6 MB
    int* s1sum = (int*)(ws + off);                 off += 1024 * 4;
    float* dis = (float*)(ws + off);               off += (size_t)N * 4;
    unsigned int* Wt = (unsigned int*)(ws + off);  off += (size_t)C * C2U * 4;

    ngl_chist_kernel<<<NBLK, 256, NBUCK * 4, stream>>>(dst, E, NBUCK, NBLK, cnt);
    ngl_s1_kernel<<<NB2, 256, 0, stream>>>(cnt, s1sum, M, W, Wt);
    ngl_s2_kernel<<<NB2, 256, 0, stream>>>(cnt, s1sum, cntoff, M, NB2);
    ngl_cscat_kernel<<<NBLK, 256, NBUCK * 4, stream>>>(src, dst, E, NBUCK, NBLK, cntoff, pk);
    ngl_f1cvt_kernel<<<NBUCK, 256, 0, stream>>>(pk, cntoff, NBLK, E, N,
                                                (const float4*)x, dis, (uint4*)xh);
    ngl_gather_kernel<<<NBUCK, 256, 0, stream>>>(xh, dis, pk, cntoff, NBLK, E, N, agg);

    int tiles = (N + 15) / 16;            // 6250
    ngl_mfma_gemm_kernel<<<512, 256, 0, stream>>>(
        (const uint4*)agg, (const uint4*)Wt, b, (float*)d_out, N, tiles);
}

// Round 14
// 1288.193 us; speedup vs baseline: 1.0003x; 1.0003x over previous
//
#include <hip/hip_runtime.h>
#include <math.h>

#define C      128
#define C2U    64         // uints (2x bf16) per row
#define BSH    6          // 64 nodes per bucket
#define BNODES 64
#define CHUNKE 16384      // edges per coarse block

typedef __attribute__((ext_vector_type(8))) short bf16x8;   // 8 bf16 = 4 VGPR
typedef __attribute__((ext_vector_type(4))) float f32x4;

union UV { uint4 u; bf16x8 h; };

// ---- bf16 helpers (manual RNE) ----
__device__ __forceinline__ unsigned int f2bf(float f) {
    unsigned int u = __float_as_uint(f);
    return (u + 0x7fffu + ((u >> 16) & 1u)) >> 16;
}
__device__ __forceinline__ float bflo(unsigned int v) { return __uint_as_float(v << 16); }
__device__ __forceinline__ float bfhi(unsigned int v) { return __uint_as_float(v & 0xffff0000u); }

// ---------------- a1: coarse histogram (LDS atomics only) ----------------
__global__ __launch_bounds__(256) void ngl_chist_kernel(
        const int* __restrict__ dst, int E, int NBUCK, int NBLK, int* __restrict__ cnt) {
    extern __shared__ int h[];
    for (int i = threadIdx.x; i < NBUCK; i += 256) h[i] = 0;
    __syncthreads();
    int base = blockIdx.x * CHUNKE;
    int end = base + CHUNKE; if (end > E) end = E;
    for (int i = base + threadIdx.x; i < end; i += 256)
        atomicAdd(&h[dst[i] >> BSH], 1);
    __syncthreads();
    for (int i = threadIdx.x; i < NBUCK; i += 256)
        cnt[i * NBLK + blockIdx.x] = h[i];
}

// ---------------- a2a: partial sums for scan; also hosts W -> W^T bf16 ----------------
__global__ __launch_bounds__(256) void ngl_s1_kernel(const int* __restrict__ in,
                                                     int* __restrict__ bsum, int M,
                                                     const float* __restrict__ W,
                                                     unsigned int* __restrict__ Wt) {
    int g = blockIdx.x * 256 + threadIdx.x;
    if (g < C * C2U) {
        int col = g >> 6, k2 = g & 63;
        float w0 = W[(2 * k2) * C + col];
        float w1 = W[(2 * k2 + 1) * C + col];
        Wt[col * C2U + k2] = f2bf(w0) | (f2bf(w1) << 16);
    }

    __shared__ int red[256];
    int t = threadIdx.x;
    int base = blockIdx.x * 1024 + t * 4;
    int s = 0;
    #pragma unroll
    for (int j = 0; j < 4; ++j) {
        int i = base + j;
        if (i < M) s += in[i];
    }
    red[t] = s;
    __syncthreads();
    for (int o = 128; o > 0; o >>= 1) {
        if (t < o) red[t] += red[t + o];
        __syncthreads();
    }
    if (t == 0) bsum[blockIdx.x] = red[0];
}

// ---------------- a2b: exclusive scan (redundant block-sum scan in LDS) ----------------
__global__ __launch_bounds__(256) void ngl_s2_kernel(
        const int* __restrict__ in, const int* __restrict__ bsum,
        int* __restrict__ out, int M, int NB) {
    __shared__ int pre[256];
    __shared__ int red[256];
    int t = threadIdx.x;
    pre[t] = (t < NB) ? bsum[t] : 0;
    __syncthreads();
    for (int o = 1; o < 256; o <<= 1) {
        int v = 0;
        if (t >= o) v = pre[t - o];
        __syncthreads();
        if (t >= o) pre[t] += v;
        __syncthreads();
    }
    int boff = (blockIdx.x == 0) ? 0 : pre[blockIdx.x - 1];

    int base = blockIdx.x * 1024 + t * 4;
    int v[4];
    int s = 0;
    #pragma unroll
    for (int j = 0; j < 4; ++j) {
        int i = base + j;
        v[j] = (i < M) ? in[i] : 0;
        s += v[j];
    }
    red[t] = s;
    __syncthreads();
    for (int o = 1; o < 256; o <<= 1) {
        int u = 0;
        if (t >= o) u = red[t - o];
        __syncthreads();
        if (t >= o) red[t] += u;
        __syncthreads();
    }
    int run = boff + ((t == 0) ? 0 : red[t - 1]);
    #pragma unroll
    for (int j = 0; j < 4; ++j) {
        int i = base + j;
        if (i < M) {
            out[i] = run;
            run += v[j];
        }
    }
}

// ---------------- a3: coarse scatter; pk = src | dstloc<<17 (loc 6 bits) ----------------
__global__ __launch_bounds__(256) void ngl_cscat_kernel(
        const int* __restrict__ src, const int* __restrict__ dst, int E,
        int NBUCK, int NBLK, const int* __restrict__ cntoff,
        unsigned int* __restrict__ pk) {
    extern __shared__ int cur[];
    int blk = blockIdx.x;
    for (int i = threadIdx.x; i < NBUCK; i += 256) cur[i] = cntoff[i * NBLK + blk];
    __syncthreads();
    int base = blk * CHUNKE;
    int end = base + CHUNKE; if (end > E) end = E;
    for (int i = base + threadIdx.x; i < end; i += 256) {
        int d = dst[i];
        int b = d >> BSH;
        int pos = atomicAdd(&cur[b], 1);
        pk[pos] = (unsigned int)src[i] | ((unsigned int)(d & (BNODES - 1)) << 17);
    }
}

// ---------------- f1cvt: per-bucket hist -> dis ; convert bucket's x rows -> xh ----------------
__global__ __launch_bounds__(256) void ngl_f1cvt_kernel(
        const unsigned int* __restrict__ pk, const int* __restrict__ cntoff,
        int NBLK, int E, int N,
        const float4* __restrict__ x4, float* __restrict__ dis,
        uint4* __restrict__ xh4) {
    __shared__ int h[BNODES];
    __shared__ float dl[BNODES];
    int b = blockIdx.x, nb = gridDim.x;
    int s = cntoff[b * NBLK];
    int e = (b + 1 < nb) ? cntoff[(b + 1) * NBLK] : E;
    int t = threadIdx.x;
    if (t < BNODES) h[t] = 0;
    __syncthreads();
    for (int i = s + t; i < e; i += 256)
        atomicAdd(&h[pk[i] >> 17], 1);
    __syncthreads();
    if (t < BNODES) {
        int n = b * BNODES + t;
        float d = rsqrtf((float)(h[t] + 1));
        dl[t] = d;
        if (n < N) dis[n] = d;
    }
    __syncthreads();
    // convert: thread t -> row r = t>>2, quarter q = t&3 (32 floats -> 4 uint4)
    int r = t >> 2, q = t & 3;
    int n = b * BNODES + r;
    if (n < N) {
        float d = dl[r];
        const float4* xr = x4 + (long long)n * 32 + q * 8;
        uint4* xo = xh4 + (long long)n * 16 + q * 4;
        #pragma unroll
        for (int j = 0; j < 4; ++j) {
            float4 a = xr[2 * j], bb = xr[2 * j + 1];
            uint4 o;
            o.x = f2bf(a.x * d) | (f2bf(a.y * d) << 16);
            o.y = f2bf(a.z * d) | (f2bf(a.w * d) << 16);
            o.z = f2bf(bb.x * d) | (f2bf(bb.y * d) << 16);
            o.w = f2bf(bb.z * d) | (f2bf(bb.w * d) << 16);
            xo[j] = o;
        }
    }
}

// ---------------- fused gather: block = bucket, LDS fp32 accumulate ----------------
// acc layout: [loc][half][lane64] -> lo parts at [loc*128+lane], hi at [loc*128+64+lane]
// (2 lanes/bank aliasing = free). agg[n] = bf16( dis[n] * (xh[n] + sum xh[src]) )
__global__ __launch_bounds__(256) void ngl_gather_kernel(
        const unsigned int* __restrict__ xh, const float* __restrict__ dis,
        const unsigned int* __restrict__ pk, const int* __restrict__ cntoff,
        int NBLK, int E, int N, unsigned int* __restrict__ agg) {
    __shared__ float acc[BNODES * 128];   // 32 KB
    int b = blockIdx.x, nb = gridDim.x;
    int s = cntoff[b * NBLK];
    int e = (b + 1 < nb) ? cntoff[(b + 1) * NBLK] : E;
    int t = threadIdx.x;
    for (int i = t; i < BNODES * 128; i += 256) acc[i] = 0.f;
    __syncthreads();

    int w = t >> 6, lane = t & 63;
    int base = s + w * 4;
    if (base < e) {
        unsigned int cp[4];
        {
            int m = e - base; if (m > 4) m = 4;
            #pragma unroll
            for (int k = 0; k < 4; ++k) cp[k] = pk[base + (k < m ? k : m - 1)];
        }
        while (base < e) {
            int nbase = base + 16;
            unsigned int np[4];
            if (nbase < e) {
                int m2 = e - nbase; if (m2 > 4) m2 = 4;
                #pragma unroll
                for (int k = 0; k < 4; ++k) np[k] = pk[nbase + (k < m2 ? k : m2 - 1)];
            }
            int m = e - base; if (m > 4) m = 4;
            unsigned int vv[4];
            #pragma unroll
            for (int k = 0; k < 4; ++k)
                vv[k] = xh[(long long)(cp[k] & 0x1FFFFu) * C2U + lane];
            #pragma unroll
            for (int k = 0; k < 4; ++k) {
                if (k < m) {
                    int loc = (int)(cp[k] >> 17);
                    atomicAdd(&acc[loc * 128 + lane],      bflo(vv[k]));
                    atomicAdd(&acc[loc * 128 + 64 + lane], bfhi(vv[k]));
                }
            }
            #pragma unroll
            for (int k = 0; k < 4; ++k) cp[k] = np[k];
            base = nbase;
        }
    }
    __syncthreads();

    // epilogue: thread t -> node r2 = t>>2, quarter q2 = t&3 -> 16 uints
    int r2 = t >> 2, q2 = t & 3;
    int n = b * BNODES + r2;
    if (n < N) {
        float d = dis[n];
        #pragma unroll
        for (int j = 0; j < 16; ++j) {
            int u = q2 * 16 + j;
            unsigned int sv = xh[(long long)n * C2U + u];
            float ax = acc[r2 * 128 + u]      + bflo(sv);
            float ay = acc[r2 * 128 + 64 + u] + bfhi(sv);
            agg[(long long)n * C2U + u] = f2bf(ax * d) | (f2bf(ay * d) << 16);
        }
    }
}

__device__ __forceinline__ float silu1(float v) {
    return v / (1.0f + __expf(-v));
}

// ---------------- MFMA GEMM: out = silu(agg @ W + b) ----------------
__global__ __launch_bounds__(256, 2) void ngl_mfma_gemm_kernel(
        const uint4* __restrict__ agg4, const uint4* __restrict__ wt4,
        const float* __restrict__ bias, float* __restrict__ out,
        int N, int tiles_total) {
    int wid  = threadIdx.x >> 6;
    int lane = threadIdx.x & 63;
    int r  = lane & 15;       // row-in-tile (A) / col-in-tile (B,D)
    int kg = lane >> 4;       // k-group 0..3

    bf16x8 bfr[8][4];
    #pragma unroll
    for (int nt = 0; nt < 8; ++nt) {
        #pragma unroll
        for (int kk = 0; kk < 4; ++kk) {
            UV u; u.u = wt4[(nt * 16 + r) * 16 + kk * 4 + kg];
            bfr[nt][kk] = u.h;
        }
    }
    float bv[8];
    #pragma unroll
    for (int nt = 0; nt < 8; ++nt) bv[nt] = bias[nt * 16 + r];

    for (int tile = blockIdx.x * 4 + wid; tile < tiles_total; tile += gridDim.x * 4) {
        int row0 = tile * 16;
        int arow = row0 + r;

        bf16x8 afr[4];
        #pragma unroll
        for (int kk = 0; kk < 4; ++kk) {
            UV u;
            u.u = (arow < N) ? agg4[(long long)arow * 16 + kk * 4 + kg]
                             : make_uint4(0, 0, 0, 0);
            afr[kk] = u.h;
        }

        f32x4 acc[8];
        #pragma unroll
        for (int nt = 0; nt < 8; ++nt) acc[nt] = (f32x4){0.f, 0.f, 0.f, 0.f};

        #pragma unroll
        for (int kk = 0; kk < 4; ++kk) {
            #pragma unroll
            for (int nt = 0; nt < 8; ++nt) {
                acc[nt] = __builtin_amdgcn_mfma_f32_16x16x32_bf16(
                    afr[kk], bfr[nt][kk], acc[nt], 0, 0, 0);
            }
        }

        #pragma unroll
        for (int nt = 0; nt < 8; ++nt) {
            #pragma unroll
            for (int j = 0; j < 4; ++j) {
                int rr = row0 + kg * 4 + j;
                if (rr < N)
                    __builtin_nontemporal_store(
                        silu1(acc[nt][j] + bv[nt]),
                        &out[(long long)rr * C + nt * 16 + r]);
            }
        }
    }
}

extern "C" void kernel_launch(void* const* d_in, const int* in_sizes, int n_in,
                              void* d_out, int out_size, void* d_ws, size_t ws_size,
                              hipStream_t stream) {
    const float* x = (const float*)d_in[0];
    const int*   ei = (const int*)d_in[1];
    const float* W = (const float*)d_in[2];
    const float* b = (const float*)d_in[3];

    int N = in_sizes[0] / C;
    int E = in_sizes[1] / 2;
    const int* src = ei;
    const int* dst = ei + E;

    int NBUCK = (N + BNODES - 1) / BNODES;        // 1563
    int NBLK  = (E + CHUNKE - 1) / CHUNKE;        // 98
    int M     = NBUCK * NBLK;                     // 153,174
    int NB2   = (M + 1023) / 1024;                // 150 (<=256 required)

    char* ws = (char*)d_ws;
    size_t off = 0;
    unsigned int* xh = (unsigned int*)(ws + off);  off += (size_t)N * C * 2;  // 25.6 MB
    unsigned int* agg = (unsigned int*)(ws + off); off += (size_t)N * C * 2;  // 25.6 MB
    unsigned int* pk = (unsigned int*)(ws + off);  off += (size_t)E * 4;      // 6.4 MB
    int* cnt = (int*)(ws + off);                   off += (size_t)M * 4;      // 0.6 MB
    int* cntoff = (int*)(ws + off);                off += (size_t)M * 4;      // 0.6 MB
    int* s1sum = (int*)(ws + off);                 off += 1024 * 4;
    float* dis = (float*)(ws + off);               off += (size_t)N * 4;
    unsigned int* Wt = (unsigned int*)(ws + off);  off += (size_t)C * C2U * 4;

    ngl_chist_kernel<<<NBLK, 256, NBUCK * 4, stream>>>(dst, E, NBUCK, NBLK, cnt);
    ngl_s1_kernel<<<NB2, 256, 0, stream>>>(cnt, s1sum, M, W, Wt);
    ngl_s2_kernel<<<NB2, 256, 0, stream>>>(cnt, s1sum, cntoff, M, NB2);
    ngl_cscat_kernel<<<NBLK, 256, NBUCK * 4, stream>>>(src, dst, E, NBUCK, NBLK, cntoff, pk);
    ngl_f1cvt_kernel<<<NBUCK, 256, 0, stream>>>(pk, cntoff, NBLK, E, N,
                                                (const float4*)x, dis, (uint4*)xh);
    ngl_gather_kernel<<<NBUCK, 256, 0, stream>>>(xh, dis, pk, cntoff, NBLK, E, N, agg);

    int tiles = (N + 15) / 16;            // 6250
    ngl_mfma_gemm_kernel<<<512, 256, 0, stream>>>(
        (const uint4*)agg, (const uint4*)Wt, b, (float*)d_out, N, tiles);
}

// Round 15
// 189.651 us; speedup vs baseline: 6.7943x; 6.7924x over previous
//
#include <hip/hip_runtime.h>
#include <math.h>

#define C      128
#define C2U    64         // uints (2x bf16) per row
#define BSH    7          // 128 nodes per coarse bucket
#define BNODES 128
#define CHUNKE 16384      // edges per coarse block

typedef __attribute__((ext_vector_type(8))) short bf16x8;   // 8 bf16 = 4 VGPR
typedef __attribute__((ext_vector_type(4))) float f32x4;

union UV { uint4 u; bf16x8 h; };

// ---- bf16 helpers (manual RNE) ----
__device__ __forceinline__ unsigned int f2bf(float f) {
    unsigned int u = __float_as_uint(f);
    return (u + 0x7fffu + ((u >> 16) & 1u)) >> 16;
}
__device__ __forceinline__ float bflo(unsigned int v) { return __uint_as_float(v << 16); }
__device__ __forceinline__ float bfhi(unsigned int v) { return __uint_as_float(v & 0xffff0000u); }

// ---------------- a1: coarse histogram (LDS atomics only) ----------------
__global__ __launch_bounds__(256) void ngl_chist_kernel(
        const int* __restrict__ dst, int E, int NBUCK, int NBLK, int* __restrict__ cnt) {
    extern __shared__ int h[];
    for (int i = threadIdx.x; i < NBUCK; i += 256) h[i] = 0;
    __syncthreads();
    int base = blockIdx.x * CHUNKE;
    int end = base + CHUNKE; if (end > E) end = E;
    for (int i = base + threadIdx.x; i < end; i += 256)
        atomicAdd(&h[dst[i] >> BSH], 1);
    __syncthreads();
    for (int i = threadIdx.x; i < NBUCK; i += 256)
        cnt[i * NBLK + blockIdx.x] = h[i];
}

// ---------------- a2a: partial sums for scan; also hosts W -> W^T bf16 ----------------
__global__ __launch_bounds__(256) void ngl_s1_kernel(const int* __restrict__ in,
                                                     int* __restrict__ bsum, int M,
                                                     const float* __restrict__ W,
                                                     unsigned int* __restrict__ Wt) {
    int g = blockIdx.x * 256 + threadIdx.x;
    if (g < C * C2U) {
        int col = g >> 6, k2 = g & 63;
        float w0 = W[(2 * k2) * C + col];
        float w1 = W[(2 * k2 + 1) * C + col];
        Wt[col * C2U + k2] = f2bf(w0) | (f2bf(w1) << 16);
    }

    __shared__ int red[256];
    int t = threadIdx.x;
    int base = blockIdx.x * 1024 + t * 4;
    int s = 0;
    #pragma unroll
    for (int j = 0; j < 4; ++j) {
        int i = base + j;
        if (i < M) s += in[i];
    }
    red[t] = s;
    __syncthreads();
    for (int o = 128; o > 0; o >>= 1) {
        if (t < o) red[t] += red[t + o];
        __syncthreads();
    }
    if (t == 0) bsum[blockIdx.x] = red[0];
}

// ---------------- a2b: exclusive scan (redundant block-sum scan in LDS) ----------------
__global__ __launch_bounds__(256) void ngl_s2_kernel(
        const int* __restrict__ in, const int* __restrict__ bsum,
        int* __restrict__ out, int M, int NB) {
    __shared__ int pre[256];
    __shared__ int red[256];
    int t = threadIdx.x;
    pre[t] = (t < NB) ? bsum[t] : 0;
    __syncthreads();
    for (int o = 1; o < 256; o <<= 1) {
        int v = 0;
        if (t >= o) v = pre[t - o];
        __syncthreads();
        if (t >= o) pre[t] += v;
        __syncthreads();
    }
    int boff = (blockIdx.x == 0) ? 0 : pre[blockIdx.x - 1];

    int base = blockIdx.x * 1024 + t * 4;
    int v[4];
    int s = 0;
    #pragma unroll
    for (int j = 0; j < 4; ++j) {
        int i = base + j;
        v[j] = (i < M) ? in[i] : 0;
        s += v[j];
    }
    red[t] = s;
    __syncthreads();
    for (int o = 1; o < 256; o <<= 1) {
        int u = 0;
        if (t >= o) u = red[t - o];
        __syncthreads();
        if (t >= o) red[t] += u;
        __syncthreads();
    }
    int run = boff + ((t == 0) ? 0 : red[t - 1]);
    #pragma unroll
    for (int j = 0; j < 4; ++j) {
        int i = base + j;
        if (i < M) {
            out[i] = run;
            run += v[j];
        }
    }
}

// ---------------- a3: coarse scatter; pk = src | dstloc<<17 ----------------
__global__ __launch_bounds__(256) void ngl_cscat_kernel(
        const int* __restrict__ src, const int* __restrict__ dst, int E,
        int NBUCK, int NBLK, const int* __restrict__ cntoff,
        unsigned int* __restrict__ pk) {
    extern __shared__ int cur[];
    int blk = blockIdx.x;
    for (int i = threadIdx.x; i < NBUCK; i += 256) cur[i] = cntoff[i * NBLK + blk];
    __syncthreads();
    int base = blk * CHUNKE;
    int end = base + CHUNKE; if (end > E) end = E;
    for (int i = base + threadIdx.x; i < end; i += 256) {
        int d = dst[i];
        int b = d >> BSH;
        int pos = atomicAdd(&cur[b], 1);
        pk[pos] = (unsigned int)src[i] | ((unsigned int)(d & (BNODES - 1)) << 17);
    }
}

// ---- f: per-bucket hist -> deg/dis/offset + fine scatter (src) + x->xh cvt ----
__global__ __launch_bounds__(256) void ngl_fcomb_kernel(
        const unsigned int* __restrict__ pk, const int* __restrict__ cntoff,
        int NBLK, int E, int N,
        int* __restrict__ deg, float* __restrict__ dis,
        int* __restrict__ offset, int* __restrict__ payload,
        const float4* __restrict__ x4, uint4* __restrict__ xh4) {
    __shared__ int h[BNODES];
    __shared__ int sc[BNODES];
    __shared__ int cur[BNODES];
    __shared__ float dl[BNODES];
    int b = blockIdx.x, nb = gridDim.x;
    int s = cntoff[b * NBLK];
    int e = (b + 1 < nb) ? cntoff[(b + 1) * NBLK] : E;
    int t = threadIdx.x;
    if (t < BNODES) h[t] = 0;
    __syncthreads();
    for (int i = s + t; i < e; i += 256)
        atomicAdd(&h[pk[i] >> 17], 1);
    __syncthreads();
    if (t < BNODES) sc[t] = h[t];
    __syncthreads();
    for (int o = 1; o < BNODES; o <<= 1) {
        int v = 0;
        if (t < BNODES && t >= o) v = sc[t - o];
        __syncthreads();
        if (t < BNODES && t >= o) sc[t] += v;
        __syncthreads();
    }
    if (t < BNODES) {
        int ex = (t == 0) ? 0 : sc[t - 1];
        cur[t] = ex;
        int n = b * BNODES + t;
        int dv = h[t];
        float d = rsqrtf((float)(dv + 1));
        dl[t] = d;
        if (n < N) {
            deg[n] = dv;
            dis[n] = d;
            offset[n] = s + ex;
        }
    }
    __syncthreads();
    for (int i = s + t; i < e; i += 256) {
        unsigned int p = pk[i];
        int loc = (int)(p >> 17);
        int pos = s + atomicAdd(&cur[loc], 1);
        payload[pos] = (int)(p & 0x1FFFFu);
    }
    // fused cvt: thread t -> row r = t>>1, half q = t&1 (16 float4 -> 8 uint4)
    {
        int r = t >> 1, q = t & 1;
        int n = b * BNODES + r;
        if (n < N) {
            float d = dl[r];
            const float4* xr = x4 + (long long)n * 32 + q * 16;
            uint4* xo = xh4 + (long long)n * 16 + q * 8;
            #pragma unroll
            for (int j = 0; j < 8; ++j) {
                float4 a = xr[2 * j], bb = xr[2 * j + 1];
                uint4 o;
                o.x = f2bf(a.x * d) | (f2bf(a.y * d) << 16);
                o.y = f2bf(a.z * d) | (f2bf(a.w * d) << 16);
                o.z = f2bf(bb.x * d) | (f2bf(bb.y * d) << 16);
                o.w = f2bf(bb.z * d) | (f2bf(bb.w * d) << 16);
                xo[j] = o;
            }
        }
    }
}

// one wave per node; 4-deep pipeline; NO per-edge weight (pre-scaled x):
// agg[n] = bf16( dis[n] * (xh[n] + sum_edges xh[src]) )
__global__ __launch_bounds__(256) void ngl_gather_kernel(
        const unsigned int* __restrict__ xh, const float* __restrict__ dis,
        const int* __restrict__ offset, const int* __restrict__ deg,
        const int* __restrict__ payload, unsigned int* __restrict__ agg, int N) {
    int node = blockIdx.x * 4 + (threadIdx.x >> 6);
    int lane = threadIdx.x & 63;
    if (node >= N) return;

    unsigned int sv = xh[(long long)node * C2U + lane];
    float accx = bflo(sv);
    float accy = bfhi(sv);

    int beg = offset[node];
    int cnt = deg[node];

    int e0, e1, e2, e3;
    int i = 0;
    if (cnt >= 4) {
        e0 = payload[beg + 0]; e1 = payload[beg + 1];
        e2 = payload[beg + 2]; e3 = payload[beg + 3];
        while (i + 4 <= cnt) {
            int c0 = e0, c1 = e1, c2 = e2, c3 = e3;
            int nb = beg + i + 4;
            if (i + 8 <= cnt) {                 // prefetch next payload group
                e0 = payload[nb + 0]; e1 = payload[nb + 1];
                e2 = payload[nb + 2]; e3 = payload[nb + 3];
            }
            unsigned int v0 = xh[(long long)c0 * C2U + lane];
            unsigned int v1 = xh[(long long)c1 * C2U + lane];
            unsigned int v2 = xh[(long long)c2 * C2U + lane];
            unsigned int v3 = xh[(long long)c3 * C2U + lane];
            accx += bflo(v0); accy += bfhi(v0);
            accx += bflo(v1); accy += bfhi(v1);
            accx += bflo(v2); accy += bfhi(v2);
            accx += bflo(v3); accy += bfhi(v3);
            i += 4;
        }
    }
    for (; i < cnt; ++i) {
        int cs = payload[beg + i];
        unsigned int v = xh[(long long)cs * C2U + lane];
        accx += bflo(v);
        accy += bfhi(v);
    }
    float dn = dis[node];
    agg[(long long)node * C2U + lane] = f2bf(accx * dn) | (f2bf(accy * dn) << 16);
}

__device__ __forceinline__ float silu1(float v) {
    return v / (1.0f + __expf(-v));
}

// ---------------- MFMA GEMM: out = silu(agg @ W + b) ----------------
__global__ __launch_bounds__(256, 2) void ngl_mfma_gemm_kernel(
        const uint4* __restrict__ agg4, const uint4* __restrict__ wt4,
        const float* __restrict__ bias, float* __restrict__ out,
        int N, int tiles_total) {
    int wid  = threadIdx.x >> 6;
    int lane = threadIdx.x & 63;
    int r  = lane & 15;       // row-in-tile (A) / col-in-tile (B,D)
    int kg = lane >> 4;       // k-group 0..3

    bf16x8 bfr[8][4];
    #pragma unroll
    for (int nt = 0; nt < 8; ++nt) {
        #pragma unroll
        for (int kk = 0; kk < 4; ++kk) {
            UV u; u.u = wt4[(nt * 16 + r) * 16 + kk * 4 + kg];
            bfr[nt][kk] = u.h;
        }
    }
    float bv[8];
    #pragma unroll
    for (int nt = 0; nt < 8; ++nt) bv[nt] = bias[nt * 16 + r];

    for (int tile = blockIdx.x * 4 + wid; tile < tiles_total; tile += gridDim.x * 4) {
        int row0 = tile * 16;
        int arow = row0 + r;

        bf16x8 afr[4];
        #pragma unroll
        for (int kk = 0; kk < 4; ++kk) {
            UV u;
            u.u = (arow < N) ? agg4[(long long)arow * 16 + kk * 4 + kg]
                             : make_uint4(0, 0, 0, 0);
            afr[kk] = u.h;
        }

        f32x4 acc[8];
        #pragma unroll
        for (int nt = 0; nt < 8; ++nt) acc[nt] = (f32x4){0.f, 0.f, 0.f, 0.f};

        #pragma unroll
        for (int kk = 0; kk < 4; ++kk) {
            #pragma unroll
            for (int nt = 0; nt < 8; ++nt) {
                acc[nt] = __builtin_amdgcn_mfma_f32_16x16x32_bf16(
                    afr[kk], bfr[nt][kk], acc[nt], 0, 0, 0);
            }
        }

        #pragma unroll
        for (int nt = 0; nt < 8; ++nt) {
            #pragma unroll
            for (int j = 0; j < 4; ++j) {
                int rr = row0 + kg * 4 + j;
                if (rr < N)
                    __builtin_nontemporal_store(
                        silu1(acc[nt][j] + bv[nt]),
                        &out[(long long)rr * C + nt * 16 + r]);
            }
        }
    }
}

extern "C" void kernel_launch(void* const* d_in, const int* in_sizes, int n_in,
                              void* d_out, int out_size, void* d_ws, size_t ws_size,
                              hipStream_t stream) {
    const float* x = (const float*)d_in[0];
    const int*   ei = (const int*)d_in[1];
    const float* W = (const float*)d_in[2];
    const float* b = (const float*)d_in[3];

    int N = in_sizes[0] / C;
    int E = in_sizes[1] / 2;
    const int* src = ei;
    const int* dst = ei + E;

    int NBUCK = (N + BNODES - 1) / BNODES;        // 782
    int NBLK  = (E + CHUNKE - 1) / CHUNKE;        // 98
    int M     = NBUCK * NBLK;                     // 76,636
    int NB2   = (M + 1023) / 1024;                // 75 (<=256 required)

    char* ws = (char*)d_ws;
    size_t off = 0;
    unsigned int* xh = (unsigned int*)(ws + off);  off += (size_t)N * C * 2;  // 25.6 MB
    unsigned int* agg = (unsigned int*)(ws + off); off += (size_t)N * C * 2;  // 25.6 MB
    unsigned int* pk = (unsigned int*)(ws + off);  off += (size_t)E * 4;      // 6.4 MB
    int* payload = (int*)(ws + off);               off += (size_t)E * 4;      // 6.4 MB
    int* cnt = (int*)(ws + off);                   off += (size_t)M * 4;      // 0.3 MB
    int* cntoff = (int*)(ws + off);                off += (size_t)M * 4;      // 0.3 MB
    int* s1sum = (int*)(ws + off);                 off += 1024 * 4;
    int* deg = (int*)(ws + off);                   off += (size_t)N * 4;
    int* offset = (int*)(ws + off);                off += (size_t)N * 4;
    float* dis = (float*)(ws + off);               off += (size_t)N * 4;
    unsigned int* Wt = (unsigned int*)(ws + off);  off += (size_t)C * C2U * 4;

    ngl_chist_kernel<<<NBLK, 256, NBUCK * 4, stream>>>(dst, E, NBUCK, NBLK, cnt);
    ngl_s1_kernel<<<NB2, 256, 0, stream>>>(cnt, s1sum, M, W, Wt);
    ngl_s2_kernel<<<NB2, 256, 0, stream>>>(cnt, s1sum, cntoff, M, NB2);
    ngl_cscat_kernel<<<NBLK, 256, NBUCK * 4, stream>>>(src, dst, E, NBUCK, NBLK, cntoff, pk);
    ngl_fcomb_kernel<<<NBUCK, 256, 0, stream>>>(pk, cntoff, NBLK, E, N,
                                                deg, dis, offset, payload,
                                                (const float4*)x, (uint4*)xh);

    ngl_gather_kernel<<<(N + 3) / 4, 256, 0, stream>>>(
        xh, dis, offset, deg, payload, agg, N);

    int tiles = (N + 15) / 16;            // 6250
    ngl_mfma_gemm_kernel<<<512, 256, 0, stream>>>(
        (const uint4*)agg, (const uint4*)Wt, b, (float*)d_out, N, tiles);
}

// Round 16
// 156.143 us; speedup vs baseline: 8.2524x; 1.2146x over previous
//
#include <hip/hip_runtime.h>
#include <math.h>

#define C      128
#define C2U    64         // uints (2x bf16) per row
#define BSH    7          // 128 nodes per coarse bucket
#define BNODES 128
#define CHUNKE 6144       // edges per coarse block (261 blocks -> full CU coverage)

typedef __attribute__((ext_vector_type(8))) short bf16x8;   // 8 bf16 = 4 VGPR
typedef __attribute__((ext_vector_type(4))) float f32x4;

union UV { uint4 u; bf16x8 h; };

// ---- bf16 helpers (manual RNE) ----
__device__ __forceinline__ unsigned int f2bf(float f) {
    unsigned int u = __float_as_uint(f);
    return (u + 0x7fffu + ((u >> 16) & 1u)) >> 16;
}
__device__ __forceinline__ float bflo(unsigned int v) { return __uint_as_float(v << 16); }
__device__ __forceinline__ float bfhi(unsigned int v) { return __uint_as_float(v & 0xffff0000u); }

// ---------------- a1: coarse histogram (LDS atomics only) ----------------
__global__ __launch_bounds__(256) void ngl_chist_kernel(
        const int* __restrict__ dst, int E, int NBUCK, int NBLK, int* __restrict__ cnt) {
    extern __shared__ int h[];
    for (int i = threadIdx.x; i < NBUCK; i += 256) h[i] = 0;
    __syncthreads();
    int base = blockIdx.x * CHUNKE;
    int end = base + CHUNKE; if (end > E) end = E;
    for (int i = base + threadIdx.x; i < end; i += 256)
        atomicAdd(&h[dst[i] >> BSH], 1);
    __syncthreads();
    for (int i = threadIdx.x; i < NBUCK; i += 256)
        cnt[i * NBLK + blockIdx.x] = h[i];
}

// ---------------- a2a: partial sums for scan; also hosts W -> W^T bf16 ----------------
__global__ __launch_bounds__(256) void ngl_s1_kernel(const int* __restrict__ in,
                                                     int* __restrict__ bsum, int M,
                                                     const float* __restrict__ W,
                                                     unsigned int* __restrict__ Wt) {
    int g = blockIdx.x * 256 + threadIdx.x;
    if (g < C * C2U) {
        int col = g >> 6, k2 = g & 63;
        float w0 = W[(2 * k2) * C + col];
        float w1 = W[(2 * k2 + 1) * C + col];
        Wt[col * C2U + k2] = f2bf(w0) | (f2bf(w1) << 16);
    }

    __shared__ int red[256];
    int t = threadIdx.x;
    int base = blockIdx.x * 1024 + t * 4;
    int s = 0;
    #pragma unroll
    for (int j = 0; j < 4; ++j) {
        int i = base + j;
        if (i < M) s += in[i];
    }
    red[t] = s;
    __syncthreads();
    for (int o = 128; o > 0; o >>= 1) {
        if (t < o) red[t] += red[t + o];
        __syncthreads();
    }
    if (t == 0) bsum[blockIdx.x] = red[0];
}

// ---------------- a2b: exclusive scan (redundant block-sum scan in LDS) ----------------
__global__ __launch_bounds__(256) void ngl_s2_kernel(
        const int* __restrict__ in, const int* __restrict__ bsum,
        int* __restrict__ out, int M, int NB) {
    __shared__ int pre[256];
    __shared__ int red[256];
    int t = threadIdx.x;
    pre[t] = (t < NB) ? bsum[t] : 0;
    __syncthreads();
    for (int o = 1; o < 256; o <<= 1) {
        int v = 0;
        if (t >= o) v = pre[t - o];
        __syncthreads();
        if (t >= o) pre[t] += v;
        __syncthreads();
    }
    int boff = (blockIdx.x == 0) ? 0 : pre[blockIdx.x - 1];

    int base = blockIdx.x * 1024 + t * 4;
    int v[4];
    int s = 0;
    #pragma unroll
    for (int j = 0; j < 4; ++j) {
        int i = base + j;
        v[j] = (i < M) ? in[i] : 0;
        s += v[j];
    }
    red[t] = s;
    __syncthreads();
    for (int o = 1; o < 256; o <<= 1) {
        int u = 0;
        if (t >= o) u = red[t - o];
        __syncthreads();
        if (t >= o) red[t] += u;
        __syncthreads();
    }
    int run = boff + ((t == 0) ? 0 : red[t - 1]);
    #pragma unroll
    for (int j = 0; j < 4; ++j) {
        int i = base + j;
        if (i < M) {
            out[i] = run;
            run += v[j];
        }
    }
}

// ---------------- a3: coarse scatter; pk = src | dstloc<<17 ----------------
__global__ __launch_bounds__(256) void ngl_cscat_kernel(
        const int* __restrict__ src, const int* __restrict__ dst, int E,
        int NBUCK, int NBLK, const int* __restrict__ cntoff,
        unsigned int* __restrict__ pk) {
    extern __shared__ int cur[];
    int blk = blockIdx.x;
    for (int i = threadIdx.x; i < NBUCK; i += 256) cur[i] = cntoff[i * NBLK + blk];
    __syncthreads();
    int base = blk * CHUNKE;
    int end = base + CHUNKE; if (end > E) end = E;
    for (int i = base + threadIdx.x; i < end; i += 256) {
        int d = dst[i];
        int b = d >> BSH;
        int pos = atomicAdd(&cur[b], 1);
        pk[pos] = (unsigned int)src[i] | ((unsigned int)(d & (BNODES - 1)) << 17);
    }
}

// ---- f: per-bucket hist -> deg/dis/offset + fine scatter (src only) ----
__global__ __launch_bounds__(256) void ngl_fcomb_kernel(
        const unsigned int* __restrict__ pk, const int* __restrict__ cntoff,
        int NBLK, int E, int N,
        int* __restrict__ deg, float* __restrict__ dis,
        int* __restrict__ offset, int* __restrict__ payload) {
    __shared__ int h[BNODES];
    __shared__ int sc[BNODES];
    __shared__ int cur[BNODES];
    int b = blockIdx.x, nb = gridDim.x;
    int s = cntoff[b * NBLK];
    int e = (b + 1 < nb) ? cntoff[(b + 1) * NBLK] : E;
    int t = threadIdx.x;
    if (t < BNODES) h[t] = 0;
    __syncthreads();
    for (int i = s + t; i < e; i += 256)
        atomicAdd(&h[pk[i] >> 17], 1);
    __syncthreads();
    if (t < BNODES) sc[t] = h[t];
    __syncthreads();
    for (int o = 1; o < BNODES; o <<= 1) {
        int v = 0;
        if (t < BNODES && t >= o) v = sc[t - o];
        __syncthreads();
        if (t < BNODES && t >= o) sc[t] += v;
        __syncthreads();
    }
    if (t < BNODES) {
        int ex = (t == 0) ? 0 : sc[t - 1];
        cur[t] = ex;
        int n = b * BNODES + t;
        if (n < N) {
            int dv = h[t];
            deg[n] = dv;
            dis[n] = rsqrtf((float)(dv + 1));
            offset[n] = s + ex;
        }
    }
    __syncthreads();
    for (int i = s + t; i < e; i += 256) {
        unsigned int p = pk[i];
        int loc = (int)(p >> 17);
        int pos = s + atomicAdd(&cur[loc], 1);
        payload[pos] = (int)(p & 0x1FFFFu);
    }
}

// ---------------- cvtx: xh[i] = bf16(x[i] * dis[node]) (coalesced 16 thr/row) ----------------
__global__ __launch_bounds__(256) void ngl_cvtx_kernel(
        const float4* __restrict__ x4, const float* __restrict__ dis,
        uint4* __restrict__ xh4, int nt) {
    int t = blockIdx.x * blockDim.x + threadIdx.x;
    if (t >= nt) return;
    int node = t >> 4;                 // 16 threads per 128-wide row
    int q = t & 15;
    float d = dis[node];
    float4 a = x4[node * 32 + q * 2], b = x4[node * 32 + q * 2 + 1];
    uint4 o;
    o.x = f2bf(a.x * d) | (f2bf(a.y * d) << 16);
    o.y = f2bf(a.z * d) | (f2bf(a.w * d) << 16);
    o.z = f2bf(b.x * d) | (f2bf(b.y * d) << 16);
    o.w = f2bf(b.z * d) | (f2bf(b.w * d) << 16);
    xh4[node * 16 + q] = o;
}

// one wave per node; 4-deep pipeline; NO per-edge weight (pre-scaled x):
// agg[n] = bf16( dis[n] * (xh[n] + sum_edges xh[src]) )
__global__ __launch_bounds__(256) void ngl_gather_kernel(
        const unsigned int* __restrict__ xh, const float* __restrict__ dis,
        const int* __restrict__ offset, const int* __restrict__ deg,
        const int* __restrict__ payload, unsigned int* __restrict__ agg, int N) {
    int node = blockIdx.x * 4 + (threadIdx.x >> 6);
    int lane = threadIdx.x & 63;
    if (node >= N) return;

    unsigned int sv = xh[(long long)node * C2U + lane];
    float accx = bflo(sv);
    float accy = bfhi(sv);

    int beg = offset[node];
    int cnt = deg[node];

    int e0, e1, e2, e3;
    int i = 0;
    if (cnt >= 4) {
        e0 = payload[beg + 0]; e1 = payload[beg + 1];
        e2 = payload[beg + 2]; e3 = payload[beg + 3];
        while (i + 4 <= cnt) {
            int c0 = e0, c1 = e1, c2 = e2, c3 = e3;
            int nb = beg + i + 4;
            if (i + 8 <= cnt) {                 // prefetch next payload group
                e0 = payload[nb + 0]; e1 = payload[nb + 1];
                e2 = payload[nb + 2]; e3 = payload[nb + 3];
            }
            unsigned int v0 = xh[(long long)c0 * C2U + lane];
            unsigned int v1 = xh[(long long)c1 * C2U + lane];
            unsigned int v2 = xh[(long long)c2 * C2U + lane];
            unsigned int v3 = xh[(long long)c3 * C2U + lane];
            accx += bflo(v0); accy += bfhi(v0);
            accx += bflo(v1); accy += bfhi(v1);
            accx += bflo(v2); accy += bfhi(v2);
            accx += bflo(v3); accy += bfhi(v3);
            i += 4;
        }
    }
    for (; i < cnt; ++i) {
        int cs = payload[beg + i];
        unsigned int v = xh[(long long)cs * C2U + lane];
        accx += bflo(v);
        accy += bfhi(v);
    }
    float dn = dis[node];
    agg[(long long)node * C2U + lane] = f2bf(accx * dn) | (f2bf(accy * dn) << 16);
}

__device__ __forceinline__ float silu1(float v) {
    return v / (1.0f + __expf(-v));
}

// ---------------- MFMA GEMM: out = silu(agg @ W + b) ----------------
__global__ __launch_bounds__(256, 2) void ngl_mfma_gemm_kernel(
        const uint4* __restrict__ agg4, const uint4* __restrict__ wt4,
        const float* __restrict__ bias, float* __restrict__ out,
        int N, int tiles_total) {
    int wid  = threadIdx.x >> 6;
    int lane = threadIdx.x & 63;
    int r  = lane & 15;       // row-in-tile (A) / col-in-tile (B,D)
    int kg = lane >> 4;       // k-group 0..3

    bf16x8 bfr[8][4];
    #pragma unroll
    for (int nt = 0; nt < 8; ++nt) {
        #pragma unroll
        for (int kk = 0; kk < 4; ++kk) {
            UV u; u.u = wt4[(nt * 16 + r) * 16 + kk * 4 + kg];
            bfr[nt][kk] = u.h;
        }
    }
    float bv[8];
    #pragma unroll
    for (int nt = 0; nt < 8; ++nt) bv[nt] = bias[nt * 16 + r];

    for (int tile = blockIdx.x * 4 + wid; tile < tiles_total; tile += gridDim.x * 4) {
        int row0 = tile * 16;
        int arow = row0 + r;

        bf16x8 afr[4];
        #pragma unroll
        for (int kk = 0; kk < 4; ++kk) {
            UV u;
            u.u = (arow < N) ? agg4[(long long)arow * 16 + kk * 4 + kg]
                             : make_uint4(0, 0, 0, 0);
            afr[kk] = u.h;
        }

        f32x4 acc[8];
        #pragma unroll
        for (int nt = 0; nt < 8; ++nt) acc[nt] = (f32x4){0.f, 0.f, 0.f, 0.f};

        #pragma unroll
        for (int kk = 0; kk < 4; ++kk) {
            #pragma unroll
            for (int nt = 0; nt < 8; ++nt) {
                acc[nt] = __builtin_amdgcn_mfma_f32_16x16x32_bf16(
                    afr[kk], bfr[nt][kk], acc[nt], 0, 0, 0);
            }
        }

        #pragma unroll
        for (int nt = 0; nt < 8; ++nt) {
            #pragma unroll
            for (int j = 0; j < 4; ++j) {
                int rr = row0 + kg * 4 + j;
                if (rr < N)
                    __builtin_nontemporal_store(
                        silu1(acc[nt][j] + bv[nt]),
                        &out[(long long)rr * C + nt * 16 + r]);
            }
        }
    }
}

extern "C" void kernel_launch(void* const* d_in, const int* in_sizes, int n_in,
                              void* d_out, int out_size, void* d_ws, size_t ws_size,
                              hipStream_t stream) {
    const float* x = (const float*)d_in[0];
    const int*   ei = (const int*)d_in[1];
    const float* W = (const float*)d_in[2];
    const float* b = (const float*)d_in[3];

    int N = in_sizes[0] / C;
    int E = in_sizes[1] / 2;
    const int* src = ei;
    const int* dst = ei + E;

    int NBUCK = (N + BNODES - 1) / BNODES;        // 782
    int NBLK  = (E + CHUNKE - 1) / CHUNKE;        // 261
    int M     = NBUCK * NBLK;                     // ~204k
    int NB2   = (M + 1023) / 1024;                // ~200 (<=256 required)

    char* ws = (char*)d_ws;
    size_t off = 0;
    unsigned int* xh = (unsigned int*)(ws + off);  off += (size_t)N * C * 2;  // 25.6 MB
    unsigned int* agg = (unsigned int*)(ws + off); off += (size_t)N * C * 2;  // 25.6 MB
    unsigned int* pk = (unsigned int*)(ws + off);  off += (size_t)E * 4;      // 6.4 MB
    int* payload = (int*)(ws + off);               off += (size_t)E * 4;      // 6.4 MB
    int* cnt = (int*)(ws + off);                   off += (size_t)M * 4;      // 0.8 MB
    int* cntoff = (int*)(ws + off);                off += (size_t)M * 4;      // 0.8 MB
    int* s1sum = (int*)(ws + off);                 off += 1024 * 4;
    int* deg = (int*)(ws + off);                   off += (size_t)N * 4;
    int* offset = (int*)(ws + off);                off += (size_t)N * 4;
    float* dis = (float*)(ws + off);               off += (size_t)N * 4;
    unsigned int* Wt = (unsigned int*)(ws + off);  off += (size_t)C * C2U * 4;

    ngl_chist_kernel<<<NBLK, 256, NBUCK * 4, stream>>>(dst, E, NBUCK, NBLK, cnt);
    ngl_s1_kernel<<<NB2, 256, 0, stream>>>(cnt, s1sum, M, W, Wt);
    ngl_s2_kernel<<<NB2, 256, 0, stream>>>(cnt, s1sum, cntoff, M, NB2);
    ngl_cscat_kernel<<<NBLK, 256, NBUCK * 4, stream>>>(src, dst, E, NBUCK, NBLK, cntoff, pk);
    ngl_fcomb_kernel<<<NBUCK, 256, 0, stream>>>(pk, cntoff, NBLK, E, N,
                                                deg, dis, offset, payload);

    int ntx = N * 16;
    ngl_cvtx_kernel<<<(ntx + 255) / 256, 256, 0, stream>>>(
        (const float4*)x, dis, (uint4*)xh, ntx);

    ngl_gather_kernel<<<(N + 3) / 4, 256, 0, stream>>>(
        xh, dis, offset, deg, payload, agg, N);

    int tiles = (N + 15) / 16;            // 6250
    ngl_mfma_gemm_kernel<<<512, 256, 0, stream>>>(
        (const uint4*)agg, (const uint4*)Wt, b, (float*)d_out, N, tiles);
}

// Round 17
// 154.956 us; speedup vs baseline: 8.3156x; 1.0077x over previous
//
#include <hip/hip_runtime.h>
#include <math.h>

#define C      128
#define C2U    64         // uints (2x bf16) per row
#define BSH    7          // 128 nodes per coarse bucket
#define BNODES 128
#define CHUNKE 6144       // edges per coarse block (261 blocks -> full CU coverage)
#define PADMAX (BNODES * 3)   // max pad per bucket (3 per node)

typedef __attribute__((ext_vector_type(8))) short bf16x8;   // 8 bf16 = 4 VGPR
typedef __attribute__((ext_vector_type(4))) float f32x4;

union UV { uint4 u; bf16x8 h; };

// ---- bf16 helpers (manual RNE) ----
__device__ __forceinline__ unsigned int f2bf(float f) {
    unsigned int u = __float_as_uint(f);
    return (u + 0x7fffu + ((u >> 16) & 1u)) >> 16;
}
__device__ __forceinline__ float bflo(unsigned int v) { return __uint_as_float(v << 16); }
__device__ __forceinline__ float bfhi(unsigned int v) { return __uint_as_float(v & 0xffff0000u); }

// ---------------- a1: coarse histogram (LDS atomics only) ----------------
__global__ __launch_bounds__(256) void ngl_chist_kernel(
        const int* __restrict__ dst, int E, int NBUCK, int NBLK, int* __restrict__ cnt) {
    extern __shared__ int h[];
    for (int i = threadIdx.x; i < NBUCK; i += 256) h[i] = 0;
    __syncthreads();
    int base = blockIdx.x * CHUNKE;
    int end = base + CHUNKE; if (end > E) end = E;
    for (int i = base + threadIdx.x; i < end; i += 256)
        atomicAdd(&h[dst[i] >> BSH], 1);
    __syncthreads();
    for (int i = threadIdx.x; i < NBUCK; i += 256)
        cnt[i * NBLK + blockIdx.x] = h[i];
}

// ---------------- a2a: partial sums for scan; also hosts W -> W^T bf16 ----------------
__global__ __launch_bounds__(256) void ngl_s1_kernel(const int* __restrict__ in,
                                                     int* __restrict__ bsum, int M,
                                                     const float* __restrict__ W,
                                                     unsigned int* __restrict__ Wt) {
    int g = blockIdx.x * 256 + threadIdx.x;
    if (g < C * C2U) {
        int col = g >> 6, k2 = g & 63;
        float w0 = W[(2 * k2) * C + col];
        float w1 = W[(2 * k2 + 1) * C + col];
        Wt[col * C2U + k2] = f2bf(w0) | (f2bf(w1) << 16);
    }

    __shared__ int red[256];
    int t = threadIdx.x;
    int base = blockIdx.x * 1024 + t * 4;
    int s = 0;
    #pragma unroll
    for (int j = 0; j < 4; ++j) {
        int i = base + j;
        if (i < M) s += in[i];
    }
    red[t] = s;
    __syncthreads();
    for (int o = 128; o > 0; o >>= 1) {
        if (t < o) red[t] += red[t + o];
        __syncthreads();
    }
    if (t == 0) bsum[blockIdx.x] = red[0];
}

// ---------------- a2b: exclusive scan (redundant block-sum scan in LDS) ----------------
__global__ __launch_bounds__(256) void ngl_s2_kernel(
        const int* __restrict__ in, const int* __restrict__ bsum,
        int* __restrict__ out, int M, int NB) {
    __shared__ int pre[256];
    __shared__ int red[256];
    int t = threadIdx.x;
    pre[t] = (t < NB) ? bsum[t] : 0;
    __syncthreads();
    for (int o = 1; o < 256; o <<= 1) {
        int v = 0;
        if (t >= o) v = pre[t - o];
        __syncthreads();
        if (t >= o) pre[t] += v;
        __syncthreads();
    }
    int boff = (blockIdx.x == 0) ? 0 : pre[blockIdx.x - 1];

    int base = blockIdx.x * 1024 + t * 4;
    int v[4];
    int s = 0;
    #pragma unroll
    for (int j = 0; j < 4; ++j) {
        int i = base + j;
        v[j] = (i < M) ? in[i] : 0;
        s += v[j];
    }
    red[t] = s;
    __syncthreads();
    for (int o = 1; o < 256; o <<= 1) {
        int u = 0;
        if (t >= o) u = red[t - o];
        __syncthreads();
        if (t >= o) red[t] += u;
        __syncthreads();
    }
    int run = boff + ((t == 0) ? 0 : red[t - 1]);
    #pragma unroll
    for (int j = 0; j < 4; ++j) {
        int i = base + j;
        if (i < M) {
            out[i] = run;
            run += v[j];
        }
    }
}

// ---------------- a3: coarse scatter; pk = src | dstloc<<17 ----------------
__global__ __launch_bounds__(256) void ngl_cscat_kernel(
        const int* __restrict__ src, const int* __restrict__ dst, int E,
        int NBUCK, int NBLK, const int* __restrict__ cntoff,
        unsigned int* __restrict__ pk) {
    extern __shared__ int cur[];
    int blk = blockIdx.x;
    for (int i = threadIdx.x; i < NBUCK; i += 256) cur[i] = cntoff[i * NBLK + blk];
    __syncthreads();
    int base = blk * CHUNKE;
    int end = base + CHUNKE; if (end > E) end = E;
    for (int i = base + threadIdx.x; i < end; i += 256) {
        int d = dst[i];
        int b = d >> BSH;
        int pos = atomicAdd(&cur[b], 1);
        pk[pos] = (unsigned int)src[i] | ((unsigned int)(d & (BNODES - 1)) << 17);
    }
}

// ---- f: per-bucket hist -> deg/dis/offset + PADDED fine scatter (src only) ----
// payload segment for bucket b starts at cntoff[b*NBLK] + b*PADMAX; each node's
// list is padded to a multiple of 4 with sentinel index N (zero row in xh).
__global__ __launch_bounds__(256) void ngl_fcomb_kernel(
        const unsigned int* __restrict__ pk, const int* __restrict__ cntoff,
        int NBLK, int E, int N,
        int* __restrict__ deg, float* __restrict__ dis,
        int* __restrict__ offset, int* __restrict__ payload) {
    __shared__ int h[BNODES];
    __shared__ int sc[BNODES];
    __shared__ int cur[BNODES];
    int b = blockIdx.x, nb = gridDim.x;
    int s = cntoff[b * NBLK];
    int e = (b + 1 < nb) ? cntoff[(b + 1) * NBLK] : E;
    int pbase = s + b * PADMAX;
    int t = threadIdx.x;
    if (t < BNODES) h[t] = 0;
    __syncthreads();
    for (int i = s + t; i < e; i += 256)
        atomicAdd(&h[pk[i] >> 17], 1);
    __syncthreads();
    if (t < BNODES) sc[t] = (h[t] + 3) & ~3;       // padded counts
    __syncthreads();
    for (int o = 1; o < BNODES; o <<= 1) {
        int v = 0;
        if (t < BNODES && t >= o) v = sc[t - o];
        __syncthreads();
        if (t < BNODES && t >= o) sc[t] += v;
        __syncthreads();
    }
    if (t < BNODES) {
        int pc = (h[t] + 3) & ~3;
        int ex = sc[t] - pc;                        // exclusive padded scan
        cur[t] = ex;
        int n = b * BNODES + t;
        if (n < N) {
            int dv = h[t];
            deg[n] = dv;
            dis[n] = rsqrtf((float)(dv + 1));
            offset[n] = pbase + ex;
        }
    }
    __syncthreads();
    for (int i = s + t; i < e; i += 256) {
        unsigned int p = pk[i];
        int loc = (int)(p >> 17);
        int pos = pbase + atomicAdd(&cur[loc], 1);
        payload[pos] = (int)(p & 0x1FFFFu);
    }
    __syncthreads();
    if (t < BNODES) {
        // fill pad slots [cur[t], sc[t]) with sentinel N (cur[t] == ex + h[t] now)
        for (int j = cur[t]; j < sc[t]; ++j)
            payload[pbase + j] = N;
    }
}

// ---------------- cvtx: xh[i] = bf16(x[i] * dis[node]); row N = zeros ----------------
__global__ __launch_bounds__(256) void ngl_cvtx_kernel(
        const float4* __restrict__ x4, const float* __restrict__ dis,
        uint4* __restrict__ xh4, int N, int nt) {
    int t = blockIdx.x * blockDim.x + threadIdx.x;
    if (t >= nt) return;
    int node = t >> 4;                 // 16 threads per 128-wide row
    int q = t & 15;
    if (node >= N) {                   // sentinel zero row
        xh4[node * 16 + q] = make_uint4(0, 0, 0, 0);
        return;
    }
    float d = dis[node];
    float4 a = x4[node * 32 + q * 2], b = x4[node * 32 + q * 2 + 1];
    uint4 o;
    o.x = f2bf(a.x * d) | (f2bf(a.y * d) << 16);
    o.y = f2bf(a.z * d) | (f2bf(a.w * d) << 16);
    o.z = f2bf(b.x * d) | (f2bf(b.y * d) << 16);
    o.w = f2bf(b.z * d) | (f2bf(b.w * d) << 16);
    xh4[node * 16 + q] = o;
}

// one wave per node; 4-deep pipeline; padded lists -> NO remainder tail;
// 32-bit index math. agg[n] = bf16( dis[n] * (xh[n] + sum_edges xh[src]) )
__global__ __launch_bounds__(256) void ngl_gather_kernel(
        const unsigned int* __restrict__ xh, const float* __restrict__ dis,
        const int* __restrict__ offset, const int* __restrict__ deg,
        const int* __restrict__ payload, unsigned int* __restrict__ agg, int N) {
    int node = blockIdx.x * 4 + (threadIdx.x >> 6);
    int lane = threadIdx.x & 63;
    if (node >= N) return;

    unsigned int sv = xh[(unsigned int)(node * C2U + lane)];
    float accx = bflo(sv);
    float accy = bfhi(sv);

    int beg = offset[node];
    int cntp = (deg[node] + 3) & ~3;    // padded count (multiple of 4)

    if (cntp > 0) {
        int e0 = payload[beg + 0], e1 = payload[beg + 1];
        int e2 = payload[beg + 2], e3 = payload[beg + 3];
        int i = 0;
        while (true) {
            int c0 = e0, c1 = e1, c2 = e2, c3 = e3;
            int nb = beg + i + 4;
            if (i + 8 <= cntp) {                // prefetch next payload group
                e0 = payload[nb + 0]; e1 = payload[nb + 1];
                e2 = payload[nb + 2]; e3 = payload[nb + 3];
            }
            unsigned int v0 = xh[(unsigned int)(c0 * C2U + lane)];
            unsigned int v1 = xh[(unsigned int)(c1 * C2U + lane)];
            unsigned int v2 = xh[(unsigned int)(c2 * C2U + lane)];
            unsigned int v3 = xh[(unsigned int)(c3 * C2U + lane)];
            accx += bflo(v0); accy += bfhi(v0);
            accx += bflo(v1); accy += bfhi(v1);
            accx += bflo(v2); accy += bfhi(v2);
            accx += bflo(v3); accy += bfhi(v3);
            i += 4;
            if (i >= cntp) break;
        }
    }
    float dn = dis[node];
    agg[(unsigned int)(node * C2U + lane)] = f2bf(accx * dn) | (f2bf(accy * dn) << 16);
}

__device__ __forceinline__ float silu1(float v) {
    return v / (1.0f + __expf(-v));
}

// ---------------- MFMA GEMM: out = silu(agg @ W + b) ----------------
__global__ __launch_bounds__(256, 2) void ngl_mfma_gemm_kernel(
        const uint4* __restrict__ agg4, const uint4* __restrict__ wt4,
        const float* __restrict__ bias, float* __restrict__ out,
        int N, int tiles_total) {
    int wid  = threadIdx.x >> 6;
    int lane = threadIdx.x & 63;
    int r  = lane & 15;       // row-in-tile (A) / col-in-tile (B,D)
    int kg = lane >> 4;       // k-group 0..3

    bf16x8 bfr[8][4];
    #pragma unroll
    for (int nt = 0; nt < 8; ++nt) {
        #pragma unroll
        for (int kk = 0; kk < 4; ++kk) {
            UV u; u.u = wt4[(nt * 16 + r) * 16 + kk * 4 + kg];
            bfr[nt][kk] = u.h;
        }
    }
    float bv[8];
    #pragma unroll
    for (int nt = 0; nt < 8; ++nt) bv[nt] = bias[nt * 16 + r];

    for (int tile = blockIdx.x * 4 + wid; tile < tiles_total; tile += gridDim.x * 4) {
        int row0 = tile * 16;
        int arow = row0 + r;

        bf16x8 afr[4];
        #pragma unroll
        for (int kk = 0; kk < 4; ++kk) {
            UV u;
            u.u = (arow < N) ? agg4[(long long)arow * 16 + kk * 4 + kg]
                             : make_uint4(0, 0, 0, 0);
            afr[kk] = u.h;
        }

        f32x4 acc[8];
        #pragma unroll
        for (int nt = 0; nt < 8; ++nt) acc[nt] = (f32x4){0.f, 0.f, 0.f, 0.f};

        #pragma unroll
        for (int kk = 0; kk < 4; ++kk) {
            #pragma unroll
            for (int nt = 0; nt < 8; ++nt) {
                acc[nt] = __builtin_amdgcn_mfma_f32_16x16x32_bf16(
                    afr[kk], bfr[nt][kk], acc[nt], 0, 0, 0);
            }
        }

        #pragma unroll
        for (int nt = 0; nt < 8; ++nt) {
            #pragma unroll
            for (int j = 0; j < 4; ++j) {
                int rr = row0 + kg * 4 + j;
                if (rr < N)
                    __builtin_nontemporal_store(
                        silu1(acc[nt][j] + bv[nt]),
                        &out[(long long)rr * C + nt * 16 + r]);
            }
        }
    }
}

extern "C" void kernel_launch(void* const* d_in, const int* in_sizes, int n_in,
                              void* d_out, int out_size, void* d_ws, size_t ws_size,
                              hipStream_t stream) {
    const float* x = (const float*)d_in[0];
    const int*   ei = (const int*)d_in[1];
    const float* W = (const float*)d_in[2];
    const float* b = (const float*)d_in[3];

    int N = in_sizes[0] / C;
    int E = in_sizes[1] / 2;
    const int* src = ei;
    const int* dst = ei + E;

    int NBUCK = (N + BNODES - 1) / BNODES;        // 782
    int NBLK  = (E + CHUNKE - 1) / CHUNKE;        // 261
    int M     = NBUCK * NBLK;                     // ~204k
    int NB2   = (M + 1023) / 1024;                // ~200 (<=256 required)

    char* ws = (char*)d_ws;
    size_t off = 0;
    unsigned int* xh = (unsigned int*)(ws + off);  off += (size_t)(N + 1) * C * 2; // 25.6 MB (+zero row)
    unsigned int* agg = (unsigned int*)(ws + off); off += (size_t)N * C * 2;       // 25.6 MB
    unsigned int* pk = (unsigned int*)(ws + off);  off += (size_t)E * 4;           // 6.4 MB
    int* payload = (int*)(ws + off);               off += ((size_t)E + (size_t)NBUCK * PADMAX + 1024) * 4;
    int* cnt = (int*)(ws + off);                   off += (size_t)M * 4;
    int* cntoff = (int*)(ws + off);                off += (size_t)M * 4;
    int* s1sum = (int*)(ws + off);                 off += 1024 * 4;
    int* deg = (int*)(ws + off);                   off += (size_t)N * 4;
    int* offset = (int*)(ws + off);                off += (size_t)N * 4;
    float* dis = (float*)(ws + off);               off += (size_t)N * 4;
    unsigned int* Wt = (unsigned int*)(ws + off);  off += (size_t)C * C2U * 4;

    ngl_chist_kernel<<<NBLK, 256, NBUCK * 4, stream>>>(dst, E, NBUCK, NBLK, cnt);
    ngl_s1_kernel<<<NB2, 256, 0, stream>>>(cnt, s1sum, M, W, Wt);
    ngl_s2_kernel<<<NB2, 256, 0, stream>>>(cnt, s1sum, cntoff, M, NB2);
    ngl_cscat_kernel<<<NBLK, 256, NBUCK * 4, stream>>>(src, dst, E, NBUCK, NBLK, cntoff, pk);
    ngl_fcomb_kernel<<<NBUCK, 256, 0, stream>>>(pk, cntoff, NBLK, E, N,
                                                deg, dis, offset, payload);

    int ntx = (N + 1) * 16;
    ngl_cvtx_kernel<<<(ntx + 255) / 256, 256, 0, stream>>>(
        (const float4*)x, dis, (uint4*)xh, N, ntx);

    ngl_gather_kernel<<<(N + 3) / 4, 256, 0, stream>>>(
        xh, dis, offset, deg, payload, agg, N);

    int tiles = (N + 15) / 16;            // 6250
    ngl_mfma_gemm_kernel<<<512, 256, 0, stream>>>(
        (const uint4*)agg, (const uint4*)Wt, b, (float*)d_out, N, tiles);
}